// Round 3
// baseline (328.841 us; speedup 1.0000x reference)
//
#include <hip/hip_runtime.h>

#define BATCH 32
#define CDIM 512
#define NCL 27
#define NPAD 28               // padded cluster row (27 + 1) -> 7 float4s
#define HWDIM 3136            // 56*56
#define NPIX (BATCH * HWDIM)  // 100352
#define TILES_PER_B 49        // 3136 / 64
#define NBLK (NPIX / 64)      // 1568 blocks, 64 pixels each
#define CPG 128               // channels per wave (512 / 4 groups)

// ---------------------------------------------------------------------------
// Kernel 1: L2-normalize the 27 codebook rows, store TRANSPOSED + padded:
// cnT[c*28 + n] so the main kernel reads 7 contiguous float4s per channel.
// ---------------------------------------------------------------------------
__global__ void norm_clusters_k(const float* __restrict__ cl,
                                float* __restrict__ cnT) {
    const int n = blockIdx.x;
    const int lane = threadIdx.x;  // 0..63
    float v[8];
    float ss = 0.f;
#pragma unroll
    for (int k = 0; k < 8; ++k) {
        v[k] = cl[n * CDIM + k * 64 + lane];
        ss += v[k] * v[k];
    }
#pragma unroll
    for (int off = 32; off > 0; off >>= 1) ss += __shfl_down(ss, off, 64);
    ss = __shfl(ss, 0, 64);
    const float rn = 1.0f / fmaxf(sqrtf(ss), 1e-12f);
#pragma unroll
    for (int k = 0; k < 8; ++k)
        cnT[(size_t)(k * 64 + lane) * NPAD + n] = v[k] * rn;
}

// ---------------------------------------------------------------------------
// Kernel 2: main. Block = 256 threads (4 waves): 64 pixels x 4 channel
// groups. One pixel per lane (P=1) -> 6272 waves for TLP; LDS cut to
// 28.7 KB -> 5 blocks/CU; __launch_bounds__(256,5) caps VGPR at ~102.
// Per channel: 1 coalesced x load (prefetched 1 ahead) + 7 broadcast
// float4 cluster loads + 28 FMAs. LDS reduce across 4 groups, softmax
// in wave 0, coalesced prob stores, per-block loss partial.
// ---------------------------------------------------------------------------
__global__ __launch_bounds__(256, 5) void cluster_main_k(
    const float* __restrict__ x, const float* __restrict__ cnT,
    float* __restrict__ out_probs,  // = d_out + 1
    float* __restrict__ partials) {
    __shared__ float red[4][NPAD][64];  // 28672 B -> 5 blocks/CU

    const int lane = threadIdx.x;  // pixel within tile
    const int g = threadIdx.y;     // channel group (wave-uniform)
    const int t = g * 64 + lane;

    const int b = blockIdx.x / TILES_PER_B;     // uniform per block
    const int tile = blockIdx.x % TILES_PER_B;  // 64-pixel tile

    const float* xp = x + ((size_t)b * CDIM + (size_t)g * CPG) * HWDIM +
                      (size_t)tile * 64 + lane;
    const int gbase = __builtin_amdgcn_readfirstlane(g * CPG);
    const float4* cl4 = (const float4*)(cnT + (size_t)gbase * NPAD);

    float acc[NCL];
#pragma unroll
    for (int n = 0; n < NCL; ++n) acc[n] = 0.f;
    float ss = 0.f;

    float xv = xp[0];
#pragma unroll 2
    for (int c = 0; c < CPG; ++c) {
        float xn = 0.f;
        if (c + 1 < CPG) xn = xp[(size_t)(c + 1) * HWDIM];  // prefetch
        float4 q[7];
#pragma unroll
        for (int k = 0; k < 7; ++k) q[k] = cl4[c * 7 + k];
        ss += xv * xv;
        const float* cv = (const float*)q;
#pragma unroll
        for (int n = 0; n < NCL; ++n) acc[n] += xv * cv[n];
        xv = xn;
    }

#pragma unroll
    for (int n = 0; n < NCL; ++n) red[g][n][lane] = acc[n];
    red[g][27][lane] = ss;
    __syncthreads();

    // reduce the 4 groups: 28*64 = 1792 values, 7 per thread
#pragma unroll
    for (int k = 0; k < 7; ++k) {
        const int v = k * 256 + t;
        const int j = v >> 6;   // 0..27
        const int px = v & 63;  // conflict-free: consecutive lanes -> px
        red[0][j][px] = red[0][j][px] + red[1][j][px] + red[2][j][px] +
                        red[3][j][px];
    }
    __syncthreads();

    // softmax: wave 0, one pixel per lane
    if (g == 0) {
        const float xs = red[0][27][lane];
        const float rn = 1.0f / fmaxf(sqrtf(xs), 1e-12f);
        float s[NCL];
        float m = -1e30f;
#pragma unroll
        for (int n = 0; n < NCL; ++n) {
            s[n] = red[0][n][lane] * rn;
            m = fmaxf(m, s[n]);
        }
        float e[NCL];
        float z = 0.f;
#pragma unroll
        for (int n = 0; n < NCL; ++n) {
            e[n] = __expf(2.0f * (s[n] - m));
            z += e[n];
        }
        const float rz = 1.0f / z;

        float* op = out_probs + (size_t)b * NCL * HWDIM +
                    (size_t)tile * 64 + lane;
        float dot = 0.f;
#pragma unroll
        for (int n = 0; n < NCL; ++n) {
            const float pr = e[n] * rz;
            op[(size_t)n * HWDIM] = pr;  // coalesced over lanes
            dot += pr * s[n];
        }
#pragma unroll
        for (int off = 32; off > 0; off >>= 1)
            dot += __shfl_down(dot, off, 64);
        if (lane == 0) partials[blockIdx.x] = dot;
    }
}

// ---------------------------------------------------------------------------
// Kernel 3: reduce 1568 per-block partials -> loss scalar
// ---------------------------------------------------------------------------
__global__ void loss_final_k(const float* __restrict__ partials,
                             float* __restrict__ out) {
    __shared__ float sm[4];
    const int t = threadIdx.x;  // 256
    float s = 0.f;
    for (int i = t; i < NBLK; i += 256) s += partials[i];
#pragma unroll
    for (int off = 32; off > 0; off >>= 1) s += __shfl_down(s, off, 64);
    if ((t & 63) == 0) sm[t >> 6] = s;
    __syncthreads();
    if (t == 0) {
        const float tot = sm[0] + sm[1] + sm[2] + sm[3];
        out[0] = -(tot / (float)NPIX);
    }
}

extern "C" void kernel_launch(void* const* d_in, const int* in_sizes, int n_in,
                              void* d_out, int out_size, void* d_ws,
                              size_t ws_size, hipStream_t stream) {
    const float* x = (const float*)d_in[0];        // [32,512,56,56]
    const float* clusters = (const float*)d_in[1]; // [27,512]
    float* out = (float*)d_out;                    // [loss | probs]
    float* cnT = (float*)d_ws;                     // transposed clusters 512*28
    float* partials = cnT + CDIM * NPAD;           // 1568 loss partials

    norm_clusters_k<<<NCL, 64, 0, stream>>>(clusters, cnT);
    cluster_main_k<<<NBLK, dim3(64, 4), 0, stream>>>(x, cnT, out + 1, partials);
    loss_final_k<<<1, 256, 0, stream>>>(partials, out);
}

// Round 4
// 310.670 us; speedup vs baseline: 1.0585x; 1.0585x over previous
//
#include <hip/hip_runtime.h>

#define BATCH 32
#define CDIM 512
#define NCL 27
#define NPAD 28               // padded cluster row -> 7 float4s
#define HWDIM 3136            // 56*56
#define NPIX (BATCH * HWDIM)  // 100352
#define PXB 128               // pixels per block (2 per lane)
#define NBLK (NPIX / PXB)     // 784
#define CPG 128               // channels per group (512 / 4)

__device__ __forceinline__ float readlane_f(float v, int lane) {
    union { float f; int i; } u;
    u.f = v;
    u.i = __builtin_amdgcn_readlane(u.i, lane);
    return u.f;
}

// ---------------------------------------------------------------------------
// Kernel 1: L2-normalize codebook rows, store transposed+padded cnT[c][28].
// ---------------------------------------------------------------------------
__global__ void norm_clusters_k(const float* __restrict__ cl,
                                float* __restrict__ cnT) {
    const int n = blockIdx.x;
    const int lane = threadIdx.x;  // 0..63
    float v[8];
    float ss = 0.f;
#pragma unroll
    for (int k = 0; k < 8; ++k) {
        v[k] = cl[n * CDIM + k * 64 + lane];
        ss += v[k] * v[k];
    }
#pragma unroll
    for (int off = 32; off > 0; off >>= 1) ss += __shfl_down(ss, off, 64);
    ss = __shfl(ss, 0, 64);
    const float rn = 1.0f / fmaxf(sqrtf(ss), 1e-12f);
#pragma unroll
    for (int k = 0; k < 8; ++k)
        cnT[(size_t)(k * 64 + lane) * NPAD + n] = v[k] * rn;
}

// ---------------------------------------------------------------------------
// Kernel 2: main. Block = 4 waves, all covering the SAME 128 pixels (2 per
// lane), channel groups 0..3. Clusters live in per-lane VGPRs (lane c owns
// channel c0+c's 27 values) and are broadcast with v_readlane — no VMEM, no
// LDS pipe in the inner loop. x loads float2, pipelined 4 deep. Two-phase
// LDS reduction (28.7 KB), register softmax, coalesced prob stores.
// ---------------------------------------------------------------------------
__global__ __launch_bounds__(256, 3) void cluster_main_k(
    const float* __restrict__ x, const float* __restrict__ cnT,
    float* __restrict__ out_probs,  // = d_out + 1
    float* __restrict__ partials) {
    __shared__ float red[2][NPAD][PXB];  // 28672 B
    __shared__ float lossred[2];

    const int lane = threadIdx.x;  // 0..63
    const int g = threadIdx.y;     // 0..3 channel group
    const int t = g * 64 + lane;

    // two pixels per lane (HWDIM even -> same batch)
    const int p0 = blockIdx.x * PXB + 2 * lane;
    const int b = p0 / HWDIM;
    const int hw = p0 - b * HWDIM;
    const float* xp =
        x + ((size_t)b * CDIM + (size_t)(g * CPG)) * HWDIM + hw;

    float2 acc[NCL];
#pragma unroll
    for (int n = 0; n < NCL; ++n) acc[n].x = acc[n].y = 0.f;
    float ssx = 0.f, ssy = 0.f;

    for (int c0 = 0; c0 < CPG; c0 += 64) {
        // lane `lane` stashes channel (g*CPG + c0 + lane)'s cluster values
        const float4* crow =
            (const float4*)(cnT + (size_t)(g * CPG + c0 + lane) * NPAD);
        float4 q[7];
#pragma unroll
        for (int k = 0; k < 7; ++k) q[k] = crow[k];
        const float* clv = (const float*)q;

        const float* xc = xp + (size_t)c0 * HWDIM;
        float2 xv[4], xn[4];
#pragma unroll
        for (int k = 0; k < 4; ++k)
            xv[k] = *(const float2*)(xc + (size_t)k * HWDIM);

        for (int c4 = 0; c4 < 16; ++c4) {
            if (c4 < 15) {
#pragma unroll
                for (int k = 0; k < 4; ++k)
                    xn[k] = *(const float2*)(xc +
                                             (size_t)(c4 * 4 + 4 + k) * HWDIM);
            }
#pragma unroll
            for (int k = 0; k < 4; ++k) {
                const int c = c4 * 4 + k;  // uniform lane index
                const float ax = xv[k].x, ay = xv[k].y;
                ssx += ax * ax;
                ssy += ay * ay;
#pragma unroll
                for (int n = 0; n < NCL; ++n) {
                    const float w = readlane_f(clv[n], c);
                    acc[n].x += ax * w;
                    acc[n].y += ay * w;
                }
            }
#pragma unroll
            for (int k = 0; k < 4; ++k) xv[k] = xn[k];
        }
    }

    // two-phase cross-group reduction (no LDS atomics, deterministic)
    if (g < 2) {
#pragma unroll
        for (int n = 0; n < NCL; ++n)
            *(float2*)&red[g][n][2 * lane] = acc[n];
        red[g][27][2 * lane] = ssx;
        red[g][27][2 * lane + 1] = ssy;
    }
    __syncthreads();
    if (g >= 2) {
        const int gg = g - 2;
#pragma unroll
        for (int n = 0; n < NCL; ++n) {
            float2 v = *(float2*)&red[gg][n][2 * lane];
            v.x += acc[n].x;
            v.y += acc[n].y;
            *(float2*)&red[gg][n][2 * lane] = v;
        }
        float2 s = *(float2*)&red[gg][27][2 * lane];
        s.x += ssx;
        s.y += ssy;
        *(float2*)&red[gg][27][2 * lane] = s;
    }
    __syncthreads();

    // softmax: waves 0,1 -> one pixel per thread
    if (t < PXB) {
        const float xs = red[0][27][t] + red[1][27][t];
        const float rn = 1.0f / fmaxf(sqrtf(xs), 1e-12f);
        float s[NCL];
        float m = -1e30f;
#pragma unroll
        for (int n = 0; n < NCL; ++n) {
            s[n] = (red[0][n][t] + red[1][n][t]) * rn;
            m = fmaxf(m, s[n]);
        }
        float e[NCL];
        float z = 0.f;
#pragma unroll
        for (int n = 0; n < NCL; ++n) {
            e[n] = __expf(2.0f * (s[n] - m));
            z += e[n];
        }
        const float rz = 1.0f / z;

        const int p = blockIdx.x * PXB + t;
        const int bb = p / HWDIM;
        const int hh = p - bb * HWDIM;
        float* op = out_probs + (size_t)bb * NCL * HWDIM + hh;
        float dot = 0.f;
#pragma unroll
        for (int n = 0; n < NCL; ++n) {
            const float pr = e[n] * rz;
            op[(size_t)n * HWDIM] = pr;  // coalesced over lanes
            dot += pr * s[n];
        }
#pragma unroll
        for (int off = 32; off > 0; off >>= 1)
            dot += __shfl_down(dot, off, 64);
        if (lane == 0) lossred[g] = dot;  // g in {0,1}
    }
    __syncthreads();
    if (t == 0) partials[blockIdx.x] = lossred[0] + lossred[1];
}

// ---------------------------------------------------------------------------
// Kernel 3: reduce 784 per-block partials -> loss scalar
// ---------------------------------------------------------------------------
__global__ void loss_final_k(const float* __restrict__ partials,
                             float* __restrict__ out) {
    __shared__ float sm[4];
    const int t = threadIdx.x;  // 256
    float s = 0.f;
    for (int i = t; i < NBLK; i += 256) s += partials[i];
#pragma unroll
    for (int off = 32; off > 0; off >>= 1) s += __shfl_down(s, off, 64);
    if ((t & 63) == 0) sm[t >> 6] = s;
    __syncthreads();
    if (t == 0) {
        const float tot = sm[0] + sm[1] + sm[2] + sm[3];
        out[0] = -(tot / (float)NPIX);
    }
}

extern "C" void kernel_launch(void* const* d_in, const int* in_sizes, int n_in,
                              void* d_out, int out_size, void* d_ws,
                              size_t ws_size, hipStream_t stream) {
    const float* x = (const float*)d_in[0];        // [32,512,56,56]
    const float* clusters = (const float*)d_in[1]; // [27,512]
    float* out = (float*)d_out;                    // [loss | probs]
    float* cnT = (float*)d_ws;                     // transposed clusters 512*28
    float* partials = cnT + CDIM * NPAD;           // 784 loss partials

    norm_clusters_k<<<NCL, 64, 0, stream>>>(clusters, cnT);
    cluster_main_k<<<NBLK, dim3(64, 4), 0, stream>>>(x, cnT, out + 1, partials);
    loss_final_k<<<1, 256, 0, stream>>>(partials, out);
}